// Round 3
// baseline (556.704 us; speedup 1.0000x reference)
//
#include <hip/hip_runtime.h>

typedef __attribute__((ext_vector_type(8))) short bf16x8;
typedef __attribute__((ext_vector_type(4))) float f32x4;

#define MFMA16(a, b, c) __builtin_amdgcn_mfma_f32_16x16x32_bf16((a), (b), (c), 0, 0, 0)

static __device__ __forceinline__ short f2bf(float f) {
  unsigned u = __builtin_bit_cast(unsigned, f);
  unsigned r = (u + 0x7FFFu + ((u >> 16) & 1u)) >> 16;
  return (short)(unsigned short)r;
}
static __device__ __forceinline__ unsigned pack2(float lo, float hi) {
  return (unsigned)(unsigned short)f2bf(lo) | ((unsigned)(unsigned short)f2bf(hi) << 16);
}

// async global->LDS, 16B per lane; LDS dest = wave-uniform base + lane*16
static __device__ __forceinline__ void glds16(const void* g, void* l) {
  __builtin_amdgcn_global_load_lds((const __attribute__((address_space(1))) unsigned*)g,
                                   (__attribute__((address_space(3))) unsigned*)l, 16, 0, 0);
}

// ---------------- fp32 -> bf16 elementwise convert (x) ----------------
__global__ __launch_bounds__(256) void cvt_bf16_kernel(const float* __restrict__ in,
                                                       short* __restrict__ out) {
  size_t i = ((size_t)blockIdx.x * 256 + threadIdx.x) * 8;
  float4 a = *(const float4*)(in + i);
  float4 b = *(const float4*)(in + i + 4);
  uint4 o;
  o.x = pack2(a.x, a.y);
  o.y = pack2(a.z, a.w);
  o.z = pack2(b.x, b.y);
  o.w = pack2(b.z, b.w);
  *(uint4*)(out + i) = o;
}

// ---------------- fp32 [R][Cc] -> bf16 [Cc][R] transpose (weights) ----------------
__global__ __launch_bounds__(256) void transpose_cvt_kernel(const float* __restrict__ in,
                                                            short* __restrict__ out, int R,
                                                            int Cc) {
  __shared__ float tile[64][65];
  int tx = threadIdx.x & 15, ty = threadIdx.x >> 4;
  int r0 = blockIdx.y * 64, c0 = blockIdx.x * 64;
#pragma unroll
  for (int i = 0; i < 4; i++) {
    int r = ty + i * 16;
    float4 v = *(const float4*)(in + (size_t)(r0 + r) * Cc + c0 + tx * 4);
    tile[r][tx * 4 + 0] = v.x;
    tile[r][tx * 4 + 1] = v.y;
    tile[r][tx * 4 + 2] = v.z;
    tile[r][tx * 4 + 3] = v.w;
  }
  __syncthreads();
#pragma unroll
  for (int i = 0; i < 4; i++) {
    int co = ty + i * 16;
    uint2 o;
    o.x = pack2(tile[tx * 4 + 0][co], tile[tx * 4 + 1][co]);
    o.y = pack2(tile[tx * 4 + 2][co], tile[tx * 4 + 3][co]);
    *(uint2*)(out + (size_t)(c0 + co) * R + r0 + tx * 4) = o;
  }
}

// ---------------- bf16 GEMM: C = A[M,K] @ Bt[N,K]^T + bias (m97 structure) ----------------
// Unpadded 128x32 LDS tiles staged via global_load_lds (lane-contiguous), with XOR
// chunk swizzle baked into staging source addrs: physical16Bchunk = logical ^ ((row>>1)&3).
// Fragment ds_read_b128 then lands 2-way on banks (free).
// MODE 0: QKV epilogue; MODE 1: y fp32
template <int MODE>
__global__ __launch_bounds__(256) void gemm_bt_kernel(const short* __restrict__ A,
                                                      const short* __restrict__ Bt,
                                                      const float* __restrict__ bias, int K,
                                                      float* __restrict__ out_y,
                                                      short* __restrict__ q_bf,
                                                      short* __restrict__ k_bf,
                                                      short* __restrict__ vt_bf,
                                                      float* __restrict__ cache) {
  __shared__ __align__(16) short As[128 * 32];
  __shared__ __align__(16) short Bs[128 * 32];
  int tid = threadIdx.x;
  int lane = tid & 63, wid = tid >> 6;
  int wr = wid >> 1, wc = wid & 1;
  int l15 = lane & 15, l4 = lane >> 4;
  int rowBase = blockIdx.y * 128, colBase = blockIdx.x * 128;

  // staging source: lane covers row (g + lane>>2), physical chunk lane&3 which must
  // hold logical chunk (lane&3) ^ ((lane>>3)&3)
  int srow = lane >> 2;
  int schunk = ((lane & 3) ^ ((lane >> 3) & 3)) * 8;
  int g0 = wid * 16, g1 = 64 + wid * 16;
  const short* Ag0 = A + (size_t)(rowBase + g0 + srow) * K + schunk;
  const short* Ag1 = A + (size_t)(rowBase + g1 + srow) * K + schunk;
  const short* Bg0 = Bt + (size_t)(colBase + g0 + srow) * K + schunk;
  const short* Bg1 = Bt + (size_t)(colBase + g1 + srow) * K + schunk;
  short* la0 = &As[g0 * 32];
  short* la1 = &As[g1 * 32];
  short* lb0 = &Bs[g0 * 32];
  short* lb1 = &Bs[g1 * 32];

  // fragment read: logical chunk l4 at row ..+l15 -> physical l4 ^ ((l15>>1)&3)
  int fchunk = (l4 ^ ((l15 >> 1) & 3)) * 8;

  f32x4 zero = {0.f, 0.f, 0.f, 0.f};
  f32x4 acc[4][4];
#pragma unroll
  for (int i = 0; i < 4; i++)
#pragma unroll
    for (int j = 0; j < 4; j++) acc[i][j] = zero;

  for (int k0 = 0; k0 < K; k0 += 32) {
    __syncthreads();  // prior iteration's fragment reads done
    glds16(Ag0 + k0, la0);
    glds16(Ag1 + k0, la1);
    glds16(Bg0 + k0, lb0);
    glds16(Bg1 + k0, lb1);
    __syncthreads();  // drains vmcnt -> LDS tiles complete
    bf16x8 af[4], bfv[4];
#pragma unroll
    for (int mt = 0; mt < 4; mt++)
      af[mt] = *(const bf16x8*)&As[(wr * 64 + mt * 16 + l15) * 32 + fchunk];
#pragma unroll
    for (int nt = 0; nt < 4; nt++)
      bfv[nt] = *(const bf16x8*)&Bs[(wc * 64 + nt * 16 + l15) * 32 + fchunk];
#pragma unroll
    for (int mt = 0; mt < 4; mt++)
#pragma unroll
      for (int nt = 0; nt < 4; nt++) acc[mt][nt] = MFMA16(af[mt], bfv[nt], acc[mt][nt]);
  }

#pragma unroll
  for (int mt = 0; mt < 4; mt++) {
#pragma unroll
    for (int nt = 0; nt < 4; nt++) {
      int col = colBase + wc * 64 + nt * 16 + l15;
      float bv = bias[col];
#pragma unroll
      for (int r = 0; r < 4; r++) {
        int row = rowBase + wr * 64 + mt * 16 + l4 * 4 + r;
        float v = acc[mt][nt][r] + bv;
        if (MODE == 0) {
          int bb = row >> 11, t = row & 2047;
          if (col < 2048) {
            // q, pre-scaled by 1/sqrt(Dh)
            q_bf[(size_t)row * 2048 + col] = f2bf(v * 0.08838834764831845f);
          } else if (col < 4096) {
            int cc = col - 2048;
            k_bf[(size_t)row * 2048 + cc] = f2bf(v);
            cache[(size_t)(bb * 2048 + t) * 4096 + cc] = v;
          } else {
            int vc = col - 4096;
            cache[(size_t)(bb * 2048 + t) * 4096 + 2048 + vc] = v;
            int hh = vc >> 7, dd = vc & 127;
            // token-permuted within each 64-token tile so attention's P-store
            // packs (col, col+16) pairs into single dword LDS writes
            int tl = t & 63;
            int pos = (tl & 32) + 2 * (tl & 15) + ((tl >> 4) & 1);
            int tp = (t & ~63) | pos;
            vt_bf[(size_t)((bb * 16 + hh) * 128 + dd) * 2048 + tp] = f2bf(v);
          }
        } else {
          out_y[(size_t)row * 2048 + col] = v;
        }
      }
    }
  }
}

// ---------------- fused causal flash attention ----------------
// grid (16, H, B), 256 threads (4 waves). Waves 0-1 own q-tile qhi=31-bx (32 rows
// each), waves 2-3 own qlo=bx. Each wave: 32 q-rows (mt=2) -> every K/V fragment
// read feeds 2 MFMAs (LDS-throughput was the bound). K/V staged via global_load_lds
// into unpadded XOR-swizzled tiles. No max-subtraction (bounded scores); row sums
// via ones-column MFMA.
#define LDP 72  // P rows: 64 + 8 pad shorts

__global__ __launch_bounds__(256) void attn_kernel(const short* __restrict__ qb,
                                                   const short* __restrict__ kb,
                                                   const short* __restrict__ vtb,
                                                   short* __restrict__ attout) {
  __shared__ __align__(16) short Ks[64 * 128];    // 16 KB, row=token (128 shorts), swizzled
  __shared__ __align__(16) short Vs[128 * 64];    // 16 KB, row=d (64 tokens), swizzled
  __shared__ __align__(16) short Ps[4][32 * LDP]; // 18.4 KB (per-wave private)

  int tid = threadIdx.x;
  int lane = tid & 63, wid = tid >> 6;
  int l15 = lane & 15, l4 = lane >> 4;
  int qlo = blockIdx.x, qhi = 31 - qlo;
  int h = blockIdx.y, b = blockIdx.z;
  int myqt = (wid < 2) ? qhi : qlo;
  int qrow0 = myqt * 64 + (wid & 1) * 32;
  size_t qkbase = (size_t)b * 2048 * 2048 + (size_t)h * 128;
  size_t vbase = (size_t)((b * 16 + h) * 128) * 2048;

  // Q fragments direct from global (one-time; A-operand layout)
  bf16x8 qf[2][4];
#pragma unroll
  for (int mt = 0; mt < 2; mt++)
#pragma unroll
    for (int kk = 0; kk < 4; kk++)
      qf[mt][kk] = *(const bf16x8*)(qb + qkbase + (size_t)(qrow0 + mt * 16 + l15) * 2048 +
                                    kk * 32 + l4 * 8);

  // K staging: instr i = j*4+wid covers rows i*4..+4; lane: row=i*4+(lane>>4),
  // physical chunk lane&15 holds logical (lane&15)^(row&7)
  int krow_l = lane >> 4;                // + i*4
  int kchunk_base = lane & 15;           // ^ ((i&1)*4 | (lane>>4))
  // V staging: instr i covers rows i*8..+8; lane: row=i*8+(lane>>3),
  // physical chunk lane&7 holds logical (lane&7)^((lane>>3)&7)
  int vrow_l = lane >> 3;
  int vchunk = ((lane & 7) ^ (vrow_l & 7)) * 8;

  // fragment-read swizzles
  int kswz = (l15 & 7);  // physical chunk = (kk*4+l4) ^ kswz
  short onev = (short)0x3F80;  // bf16 1.0
  bf16x8 ones = {onev, onev, onev, onev, onev, onev, onev, onev};

  f32x4 zero = {0.f, 0.f, 0.f, 0.f};
  f32x4 o[2][8], ol[2];
#pragma unroll
  for (int mt = 0; mt < 2; mt++) {
    ol[mt] = zero;
#pragma unroll
    for (int n = 0; n < 8; n++) o[mt][n] = zero;
  }

  for (int kt = 0; kt <= qhi; kt++) {
    int kt0 = kt * 64;
    __syncthreads();  // prior iteration's fragment reads done
#pragma unroll
    for (int j = 0; j < 4; j++) {
      int i = j * 4 + wid;
      int krow = i * 4 + krow_l;
      int kchunk = (kchunk_base ^ (((i & 1) * 4) | krow_l)) * 8;
      glds16(kb + qkbase + (size_t)(kt0 + krow) * 2048 + kchunk, &Ks[i * 4 * 128]);
    }
#pragma unroll
    for (int j = 0; j < 4; j++) {
      int i = j * 4 + wid;
      int vrow = i * 8 + vrow_l;
      glds16(vtb + vbase + (size_t)vrow * 2048 + kt0 + vchunk, &Vs[i * 8 * 64]);
    }
    __syncthreads();  // drains vmcnt

    if (wid < 2 || kt <= qlo) {
      // S = Q K^T (q pre-scaled by 1/sqrt(Dh))
      f32x4 s[2][4];
#pragma unroll
      for (int mt = 0; mt < 2; mt++)
#pragma unroll
        for (int nt = 0; nt < 4; nt++) s[mt][nt] = zero;
#pragma unroll
      for (int kk = 0; kk < 4; kk++) {
#pragma unroll
        for (int nt = 0; nt < 4; nt++) {
          int p = (kk * 4 + l4) ^ kswz;
          bf16x8 kf = *(const bf16x8*)&Ks[(nt * 16 + l15) * 128 + p * 8];
#pragma unroll
          for (int mt = 0; mt < 2; mt++) s[mt][nt] = MFMA16(qf[mt][kk], kf, s[mt][nt]);
        }
      }

      if (kt == myqt) {  // diagonal tile: causal mask
#pragma unroll
        for (int mt = 0; mt < 2; mt++)
#pragma unroll
          for (int nt = 0; nt < 4; nt++) {
            int colg = kt0 + nt * 16 + l15;
#pragma unroll
            for (int r = 0; r < 4; r++) {
              int rowg = qrow0 + mt * 16 + l4 * 4 + r;
              if (colg > rowg) s[mt][nt][r] = -1e30f;
            }
          }
      }

      // P = exp(S), packed-pair dword LDS writes at token-permuted positions
#pragma unroll
      for (int mt = 0; mt < 2; mt++)
#pragma unroll
        for (int r = 0; r < 4; r++) {
          float p0 = __expf(s[mt][0][r]);
          float p1 = __expf(s[mt][1][r]);
          float p2 = __expf(s[mt][2][r]);
          float p3 = __expf(s[mt][3][r]);
          int prow = (mt * 16 + l4 * 4 + r) * LDP;
          *(unsigned*)&Ps[wid][prow + 2 * l15] = pack2(p0, p1);
          *(unsigned*)&Ps[wid][prow + 32 + 2 * l15] = pack2(p2, p3);
        }

      // O += P @ V ; l += P @ 1 (V fragments reused across both mt)
#pragma unroll
      for (int kk = 0; kk < 2; kk++) {
        bf16x8 pf[2];
#pragma unroll
        for (int mt = 0; mt < 2; mt++) {
          pf[mt] = *(const bf16x8*)&Ps[wid][(mt * 16 + l15) * LDP + kk * 32 + l4 * 8];
          ol[mt] = MFMA16(pf[mt], ones, ol[mt]);
        }
#pragma unroll
        for (int n = 0; n < 8; n++) {
          int p = (kk * 4 + l4) ^ kswz;  // same xor rule, 8 chunks
          bf16x8 vf = *(const bf16x8*)&Vs[(n * 16 + l15) * 64 + (p & 7) * 8];
#pragma unroll
          for (int mt = 0; mt < 2; mt++) o[mt][n] = MFMA16(pf[mt], vf, o[mt][n]);
        }
      }
    }
  }

#pragma unroll
  for (int mt = 0; mt < 2; mt++) {
    float rl[4];
#pragma unroll
    for (int r = 0; r < 4; r++) rl[r] = 1.0f / ol[mt][r];
#pragma unroll
    for (int n = 0; n < 8; n++)
#pragma unroll
      for (int r = 0; r < 4; r++)
        attout[qkbase + (size_t)(qrow0 + mt * 16 + l4 * 4 + r) * 2048 + n * 16 + l15] =
            f2bf(o[mt][n][r] * rl[r]);
  }
}

// ---------------- launch ----------------
extern "C" void kernel_launch(void* const* d_in, const int* in_sizes, int n_in, void* d_out,
                              int out_size, void* d_ws, size_t ws_size, hipStream_t stream) {
  const float* x = (const float*)d_in[0];
  // d_in[1] = attention_mask: causal, implemented analytically
  const float* W_attn = (const float*)d_in[2];
  const float* b_attn = (const float*)d_in[3];
  const float* W_proj = (const float*)d_in[4];
  const float* b_proj = (const float*)d_in[5];
  float* y = (float*)d_out;
  float* cache = y + (size_t)4096 * 2048;

  char* p = (char*)d_ws;  // ~112 MB total
  short* x_bf = (short*)p;   p += (size_t)8388608 * 2;
  short* q_bf = (short*)p;   p += (size_t)8388608 * 2;
  short* k_bf = (short*)p;   p += (size_t)8388608 * 2;
  short* vt_bf = (short*)p;  p += (size_t)8388608 * 2;
  short* att_bf = (short*)p; p += (size_t)8388608 * 2;
  short* wt_attn = (short*)p; p += (size_t)12582912 * 2;
  short* wt_proj = (short*)p; p += (size_t)4194304 * 2;

  cvt_bf16_kernel<<<4096, 256, 0, stream>>>(x, x_bf);
  transpose_cvt_kernel<<<dim3(96, 32), 256, 0, stream>>>(W_attn, wt_attn, 2048, 6144);
  transpose_cvt_kernel<<<dim3(32, 32), 256, 0, stream>>>(W_proj, wt_proj, 2048, 2048);
  gemm_bt_kernel<0><<<dim3(48, 32), 256, 0, stream>>>(x_bf, wt_attn, b_attn, 2048, nullptr, q_bf,
                                                      k_bf, vt_bf, cache);
  attn_kernel<<<dim3(16, 16, 2), 256, 0, stream>>>(q_bf, k_bf, vt_bf, att_bf);
  gemm_bt_kernel<1><<<dim3(16, 32), 256, 0, stream>>>(att_bf, wt_proj, b_proj, 2048, y, nullptr,
                                                      nullptr, nullptr, nullptr);
}

// Round 4
// 484.817 us; speedup vs baseline: 1.1483x; 1.1483x over previous
//
#include <hip/hip_runtime.h>

typedef __attribute__((ext_vector_type(8))) short bf16x8;
typedef __attribute__((ext_vector_type(4))) float f32x4;

#define MFMA16(a, b, c) __builtin_amdgcn_mfma_f32_16x16x32_bf16((a), (b), (c), 0, 0, 0)

static __device__ __forceinline__ short f2bf(float f) {
  unsigned u = __builtin_bit_cast(unsigned, f);
  unsigned r = (u + 0x7FFFu + ((u >> 16) & 1u)) >> 16;
  return (short)(unsigned short)r;
}
static __device__ __forceinline__ unsigned pack2(float lo, float hi) {
  return (unsigned)(unsigned short)f2bf(lo) | ((unsigned)(unsigned short)f2bf(hi) << 16);
}

// async global->LDS, 16B per lane
static __device__ __forceinline__ void glds16(const void* g, void* l) {
  __builtin_amdgcn_global_load_lds((const __attribute__((address_space(1))) unsigned*)g,
                                   (__attribute__((address_space(3))) unsigned*)l, 16, 0, 0);
}

// ---------------- fp32 -> bf16 elementwise convert (x) ----------------
__global__ __launch_bounds__(256) void cvt_bf16_kernel(const float* __restrict__ in,
                                                       short* __restrict__ out) {
  size_t i = ((size_t)blockIdx.x * 256 + threadIdx.x) * 8;
  float4 a = *(const float4*)(in + i);
  float4 b = *(const float4*)(in + i + 4);
  uint4 o;
  o.x = pack2(a.x, a.y);
  o.y = pack2(a.z, a.w);
  o.z = pack2(b.x, b.y);
  o.w = pack2(b.z, b.w);
  *(uint4*)(out + i) = o;
}

// ---------------- fp32 [R][Cc] -> bf16 [Cc][R] transpose (weights) ----------------
__global__ __launch_bounds__(256) void transpose_cvt_kernel(const float* __restrict__ in,
                                                            short* __restrict__ out, int R,
                                                            int Cc) {
  __shared__ float tile[64][65];
  int tx = threadIdx.x & 15, ty = threadIdx.x >> 4;
  int r0 = blockIdx.y * 64, c0 = blockIdx.x * 64;
#pragma unroll
  for (int i = 0; i < 4; i++) {
    int r = ty + i * 16;
    float4 v = *(const float4*)(in + (size_t)(r0 + r) * Cc + c0 + tx * 4);
    tile[r][tx * 4 + 0] = v.x;
    tile[r][tx * 4 + 1] = v.y;
    tile[r][tx * 4 + 2] = v.z;
    tile[r][tx * 4 + 3] = v.w;
  }
  __syncthreads();
#pragma unroll
  for (int i = 0; i < 4; i++) {
    int co = ty + i * 16;
    uint2 o;
    o.x = pack2(tile[tx * 4 + 0][co], tile[tx * 4 + 1][co]);
    o.y = pack2(tile[tx * 4 + 2][co], tile[tx * 4 + 3][co]);
    *(uint2*)(out + (size_t)(c0 + co) * R + r0 + tx * 4) = o;
  }
}

// ---------------- QKV GEMM (128x128 tile, glds staging, m97 structure) ----------------
// Epilogue: q scaled->q_bf, k->k_bf + cache fp32, v-> v_bf (row-major, coalesced) + cache fp32.
// The vt transpose/permute moved to vpost_kernel (was a 16-line/instr scatter here).
__global__ __launch_bounds__(256) void gemm_qkv_kernel(const short* __restrict__ A,
                                                       const short* __restrict__ Bt,
                                                       const float* __restrict__ bias,
                                                       short* __restrict__ q_bf,
                                                       short* __restrict__ k_bf,
                                                       short* __restrict__ v_bf,
                                                       float* __restrict__ cache) {
  const int K = 2048;
  __shared__ __align__(16) short As[128 * 32];
  __shared__ __align__(16) short Bs[128 * 32];
  int tid = threadIdx.x;
  int lane = tid & 63, wid = tid >> 6;
  int wr = wid >> 1, wc = wid & 1;
  int l15 = lane & 15, l4 = lane >> 4;
  int rowBase = blockIdx.y * 128, colBase = blockIdx.x * 128;

  int srow = lane >> 2;
  int schunk = ((lane & 3) ^ ((lane >> 3) & 3)) * 8;
  int g0 = wid * 16, g1 = 64 + wid * 16;
  const short* Ag0 = A + (size_t)(rowBase + g0 + srow) * K + schunk;
  const short* Ag1 = A + (size_t)(rowBase + g1 + srow) * K + schunk;
  const short* Bg0 = Bt + (size_t)(colBase + g0 + srow) * K + schunk;
  const short* Bg1 = Bt + (size_t)(colBase + g1 + srow) * K + schunk;
  short* la0 = &As[g0 * 32];
  short* la1 = &As[g1 * 32];
  short* lb0 = &Bs[g0 * 32];
  short* lb1 = &Bs[g1 * 32];

  int fchunk = (l4 ^ ((l15 >> 1) & 3)) * 8;

  f32x4 zero = {0.f, 0.f, 0.f, 0.f};
  f32x4 acc[4][4];
#pragma unroll
  for (int i = 0; i < 4; i++)
#pragma unroll
    for (int j = 0; j < 4; j++) acc[i][j] = zero;

  for (int k0 = 0; k0 < K; k0 += 32) {
    __syncthreads();
    glds16(Ag0 + k0, la0);
    glds16(Ag1 + k0, la1);
    glds16(Bg0 + k0, lb0);
    glds16(Bg1 + k0, lb1);
    __syncthreads();
    bf16x8 af[4], bfv[4];
#pragma unroll
    for (int mt = 0; mt < 4; mt++)
      af[mt] = *(const bf16x8*)&As[(wr * 64 + mt * 16 + l15) * 32 + fchunk];
#pragma unroll
    for (int nt = 0; nt < 4; nt++)
      bfv[nt] = *(const bf16x8*)&Bs[(wc * 64 + nt * 16 + l15) * 32 + fchunk];
#pragma unroll
    for (int mt = 0; mt < 4; mt++)
#pragma unroll
      for (int nt = 0; nt < 4; nt++) acc[mt][nt] = MFMA16(af[mt], bfv[nt], acc[mt][nt]);
  }

#pragma unroll
  for (int mt = 0; mt < 4; mt++) {
#pragma unroll
    for (int nt = 0; nt < 4; nt++) {
      int col = colBase + wc * 64 + nt * 16 + l15;
      float bv = bias[col];
#pragma unroll
      for (int r = 0; r < 4; r++) {
        int row = rowBase + wr * 64 + mt * 16 + l4 * 4 + r;
        float v = acc[mt][nt][r] + bv;
        int bb = row >> 11, t = row & 2047;
        if (col < 2048) {
          q_bf[(size_t)row * 2048 + col] = f2bf(v * 0.08838834764831845f);
        } else if (col < 4096) {
          int cc = col - 2048;
          k_bf[(size_t)row * 2048 + cc] = f2bf(v);
          cache[(size_t)(bb * 2048 + t) * 4096 + cc] = v;
        } else {
          int vc = col - 4096;
          cache[(size_t)(bb * 2048 + t) * 4096 + 2048 + vc] = v;
          v_bf[(size_t)row * 2048 + vc] = f2bf(v);  // coalesced; transposed later
        }
      }
    }
  }
}

// ---------------- v_bf [B*T][H*Dh] -> vt_bf [(b*16+h)*128+d][t-permuted] ----------------
// grid (T/64, Dh/64, B*H), 256 thr. LDS tile transpose; writes contiguous uint4 at
// permuted token positions (inverse permute applied on the LDS read side).
__global__ __launch_bounds__(256) void vpost_kernel(const short* __restrict__ vb,
                                                    short* __restrict__ vt) {
  __shared__ short tile[64][72];
  int tid = threadIdx.x;
  int z = blockIdx.z;  // b*16+h
  int b = z >> 4, hh = z & 15;
  int t0 = blockIdx.x * 64, d0 = blockIdx.y * 64;
  int tx = tid & 7, ty = tid >> 3;  // 32 rows per pass
#pragma unroll
  for (int i = 0; i < 2; i++) {
    int r = ty + i * 32;
    *(uint4*)&tile[r][tx * 8] =
        *(const uint4*)(vb + (size_t)(b * 2048 + t0 + r) * 2048 + hh * 128 + d0 + tx * 8);
  }
  __syncthreads();
#pragma unroll
  for (int i = 0; i < 2; i++) {
    int dr = ty + i * 32;
    short tmp[8];
#pragma unroll
    for (int j = 0; j < 8; j++) {
      int p = tx * 8 + j;
      // inverse of pos(tl) = (tl&32) + 2*(tl&15) + ((tl>>4)&1)
      int tl = (p & 32) + ((p & 1) << 4) + ((p >> 1) & 15);
      tmp[j] = tile[tl][dr];
    }
    *(uint4*)(vt + (size_t)(z * 128 + d0 + dr) * 2048 + t0 + tx * 8) = *(uint4*)tmp;
  }
}

// ---------------- proj GEMM (64x128 tile, register-staged, 1024 blocks) ----------------
#define LDT 40
__global__ __launch_bounds__(256) void gemm_proj_kernel(const short* __restrict__ A,
                                                        const short* __restrict__ Bt,
                                                        const float* __restrict__ bias,
                                                        float* __restrict__ out_y) {
  const int K = 2048;
  __shared__ short As[64 * LDT];
  __shared__ short Bs[128 * LDT];
  int tid = threadIdx.x;
  int lane = tid & 63, wid = tid >> 6;
  int wr = wid >> 1, wc = wid & 1;  // wave covers rows wr*32, cols wc*64
  int l15 = lane & 15, l4 = lane >> 4;
  int rowBase = blockIdx.y * 64, colBase = blockIdx.x * 128;
  int srow = tid >> 2, skc = (tid & 3) * 8;

  f32x4 zero = {0.f, 0.f, 0.f, 0.f};
  f32x4 acc[2][4];
#pragma unroll
  for (int i = 0; i < 2; i++)
#pragma unroll
    for (int j = 0; j < 4; j++) acc[i][j] = zero;

  const short* Ap0 = A + (size_t)(rowBase + srow) * K + skc;
  const short* Bp0 = Bt + (size_t)(colBase + srow) * K + skc;
  const short* Bp1 = Bt + (size_t)(colBase + srow + 64) * K + skc;

  for (int k0 = 0; k0 < K; k0 += 32) {
    uint4 a0 = *(const uint4*)(Ap0 + k0);
    uint4 b0 = *(const uint4*)(Bp0 + k0);
    uint4 b1 = *(const uint4*)(Bp1 + k0);
    __syncthreads();
    *(uint4*)&As[srow * LDT + skc] = a0;
    *(uint4*)&Bs[srow * LDT + skc] = b0;
    *(uint4*)&Bs[(srow + 64) * LDT + skc] = b1;
    __syncthreads();
    bf16x8 af[2], bfv[4];
#pragma unroll
    for (int mt = 0; mt < 2; mt++)
      af[mt] = *(const bf16x8*)&As[(wr * 32 + mt * 16 + l15) * LDT + l4 * 8];
#pragma unroll
    for (int nt = 0; nt < 4; nt++)
      bfv[nt] = *(const bf16x8*)&Bs[(wc * 64 + nt * 16 + l15) * LDT + l4 * 8];
#pragma unroll
    for (int mt = 0; mt < 2; mt++)
#pragma unroll
      for (int nt = 0; nt < 4; nt++) acc[mt][nt] = MFMA16(af[mt], bfv[nt], acc[mt][nt]);
  }

#pragma unroll
  for (int mt = 0; mt < 2; mt++) {
#pragma unroll
    for (int nt = 0; nt < 4; nt++) {
      int col = colBase + wc * 64 + nt * 16 + l15;
      float bv = bias[col];
#pragma unroll
      for (int r = 0; r < 4; r++) {
        int row = rowBase + wr * 32 + mt * 16 + l4 * 4 + r;
        out_y[(size_t)row * 2048 + col] = acc[mt][nt][r] + bv;
      }
    }
  }
}

// ---------------- fused causal flash attention (R2 proven version) ----------------
#define LDK 136  // K rows: 128 + 8 pad shorts
#define LDV 72   // V rows: 64 + 8 pad
#define LDP 72   // P rows: 64 + 8 pad

__global__ __launch_bounds__(512, 4) void attn_kernel(const short* __restrict__ qb,
                                                      const short* __restrict__ kb,
                                                      const short* __restrict__ vtb,
                                                      short* __restrict__ attout) {
  __shared__ short Ks[64 * LDK];
  __shared__ short Vs[128 * LDV];
  __shared__ short Ps[8][16 * LDP];

  int tid = threadIdx.x;
  int lane = tid & 63, wid = tid >> 6;
  int l15 = lane & 15, l4 = lane >> 4;
  int qlo = blockIdx.x, qhi = 31 - qlo;
  int h = blockIdx.y, b = blockIdx.z;
  int myqt = (wid < 4) ? qhi : qlo;
  int qrow0 = myqt * 64 + (wid & 3) * 16;
  size_t qkbase = (size_t)b * 2048 * 2048 + (size_t)h * 128;
  size_t vbase = (size_t)((b * 16 + h) * 128) * 2048;

  bf16x8 qf[4];
#pragma unroll
  for (int kk = 0; kk < 4; kk++)
    qf[kk] = *(const bf16x8*)(qb + qkbase + (size_t)(qrow0 + l15) * 2048 + kk * 32 + l4 * 8);

  short onev = (short)0x3F80;  // bf16 1.0
  bf16x8 ones = {onev, onev, onev, onev, onev, onev, onev, onev};

  f32x4 zero = {0.f, 0.f, 0.f, 0.f};
  f32x4 o[8], ol;
#pragma unroll
  for (int n = 0; n < 8; n++) o[n] = zero;
  ol = zero;

  for (int kt = 0; kt <= qhi; kt++) {
    int kt0 = kt * 64;
    __syncthreads();
#pragma unroll
    for (int i = 0; i < 2; i++) {
      int c = i * 512 + tid;
      int kr = c >> 4, kc = (c & 15) * 8;
      *(uint4*)&Ks[kr * LDK + kc] = *(const uint4*)(kb + qkbase + (size_t)(kt0 + kr) * 2048 + kc);
    }
#pragma unroll
    for (int i = 0; i < 2; i++) {
      int c = i * 512 + tid;
      int dr = c >> 3, tc = (c & 7) * 8;
      *(uint4*)&Vs[dr * LDV + tc] = *(const uint4*)(vtb + vbase + (size_t)dr * 2048 + kt0 + tc);
    }
    __syncthreads();

    if (wid < 4 || kt <= qlo) {
      f32x4 s[4];
#pragma unroll
      for (int nt = 0; nt < 4; nt++) s[nt] = zero;
#pragma unroll
      for (int kk = 0; kk < 4; kk++) {
#pragma unroll
        for (int nt = 0; nt < 4; nt++) {
          bf16x8 kf = *(const bf16x8*)&Ks[(nt * 16 + l15) * LDK + kk * 32 + l4 * 8];
          s[nt] = MFMA16(qf[kk], kf, s[nt]);
        }
      }

      if (kt == myqt) {
#pragma unroll
        for (int nt = 0; nt < 4; nt++) {
          int colg = kt0 + nt * 16 + l15;
#pragma unroll
          for (int r = 0; r < 4; r++) {
            int rowg = qrow0 + l4 * 4 + r;
            if (colg > rowg) s[nt][r] = -1e30f;
          }
        }
      }

#pragma unroll
      for (int r = 0; r < 4; r++) {
        float p0 = __expf(s[0][r]);
        float p1 = __expf(s[1][r]);
        float p2 = __expf(s[2][r]);
        float p3 = __expf(s[3][r]);
        int prow = (l4 * 4 + r) * LDP;
        *(unsigned*)&Ps[wid][prow + 2 * l15] = pack2(p0, p1);
        *(unsigned*)&Ps[wid][prow + 32 + 2 * l15] = pack2(p2, p3);
      }

#pragma unroll
      for (int kk = 0; kk < 2; kk++) {
        bf16x8 pf = *(const bf16x8*)&Ps[wid][l15 * LDP + kk * 32 + l4 * 8];
        ol = MFMA16(pf, ones, ol);
#pragma unroll
        for (int n = 0; n < 8; n++) {
          bf16x8 vf = *(const bf16x8*)&Vs[(n * 16 + l15) * LDV + kk * 32 + l4 * 8];
          o[n] = MFMA16(pf, vf, o[n]);
        }
      }
    }
  }

  float rl[4];
#pragma unroll
  for (int r = 0; r < 4; r++) rl[r] = 1.0f / ol[r];
#pragma unroll
  for (int n = 0; n < 8; n++)
#pragma unroll
    for (int r = 0; r < 4; r++)
      attout[qkbase + (size_t)(qrow0 + l4 * 4 + r) * 2048 + n * 16 + l15] =
          f2bf(o[n][r] * rl[r]);
}

// ---------------- launch ----------------
extern "C" void kernel_launch(void* const* d_in, const int* in_sizes, int n_in, void* d_out,
                              int out_size, void* d_ws, size_t ws_size, hipStream_t stream) {
  const float* x = (const float*)d_in[0];
  const float* W_attn = (const float*)d_in[2];
  const float* b_attn = (const float*)d_in[3];
  const float* W_proj = (const float*)d_in[4];
  const float* b_proj = (const float*)d_in[5];
  float* y = (float*)d_out;
  float* cache = y + (size_t)4096 * 2048;

  char* p = (char*)d_ws;
  short* x_bf = (short*)p;   p += (size_t)8388608 * 2;
  short* q_bf = (short*)p;   p += (size_t)8388608 * 2;
  short* k_bf = (short*)p;   p += (size_t)8388608 * 2;
  short* vt_bf = (short*)p;  p += (size_t)8388608 * 2;
  short* att_bf = (short*)p; p += (size_t)8388608 * 2;  // also v_bf (consumed before attn writes)
  short* wt_attn = (short*)p; p += (size_t)12582912 * 2;
  short* wt_proj = (short*)p; p += (size_t)4194304 * 2;
  short* v_bf = att_bf;  // alias: gemm_qkv writes, vpost reads, then attn overwrites

  cvt_bf16_kernel<<<4096, 256, 0, stream>>>(x, x_bf);
  transpose_cvt_kernel<<<dim3(96, 32), 256, 0, stream>>>(W_attn, wt_attn, 2048, 6144);
  transpose_cvt_kernel<<<dim3(32, 32), 256, 0, stream>>>(W_proj, wt_proj, 2048, 2048);
  gemm_qkv_kernel<<<dim3(48, 32), 256, 0, stream>>>(x_bf, wt_attn, b_attn, q_bf, k_bf, v_bf,
                                                    cache);
  vpost_kernel<<<dim3(32, 2, 32), 256, 0, stream>>>(v_bf, vt_bf);
  attn_kernel<<<dim3(16, 16, 2), 512, 0, stream>>>(q_bf, k_bf, vt_bf, att_bf);
  gemm_proj_kernel<<<dim3(16, 64), 256, 0, stream>>>(att_bf, wt_proj, b_proj, y);
}